// Round 6
// baseline (826.302 us; speedup 1.0000x reference)
//
#include <hip/hip_runtime.h>
#include <math.h>

#define BB 8
#define NN 1024
#define DD 1024
#define HH 16
#define SS 64
#define BH (BB*HH)

typedef _Float16 half8 __attribute__((ext_vector_type(8)));
typedef _Float16 half4v __attribute__((ext_vector_type(4)));
typedef float floatx4 __attribute__((ext_vector_type(4)));

#define MFMA16(A, B, C) __builtin_amdgcn_mfma_f32_16x16x32_f16((A), (B), (C), 0, 0, 0)

// ---------------- Pre-pass: split X into fp16 hi/lo ----------------
__global__ __launch_bounds__(256) void split_x(
    const float* __restrict__ X, _Float16* __restrict__ Xh, _Float16* __restrict__ Xl)
{
    int idx = (blockIdx.x * 256 + threadIdx.x) * 4;
    float4 x4 = *(const float4*)(X + idx);
    float xs[4] = {x4.x, x4.y, x4.z, x4.w};
    half4v h, l;
    #pragma unroll
    for (int i = 0; i < 4; i++) {
        _Float16 hi = (_Float16)xs[i];
        h[i] = hi;
        l[i] = (_Float16)(xs[i] - (float)hi);
    }
    *(half4v*)(Xh + idx) = h;
    *(half4v*)(Xl + idx) = l;
}

// ---------------- Pre-pass: split + transpose W ----------------
__global__ __launch_bounds__(256) void split_wt(
    const float* __restrict__ W, _Float16* __restrict__ Wth, _Float16* __restrict__ Wtl)
{
    __shared__ float tile[64][68];
    const int hc = blockIdx.x, d0 = blockIdx.y * 64;
    const int t = threadIdx.x;
    {
        int i = t >> 2, sq = (t & 3) * 16;
        const float* src = W + ((size_t)hc * DD + d0 + i) * SS + sq;
        #pragma unroll
        for (int u = 0; u < 4; u++) {
            float4 v = *(const float4*)(src + 4 * u);
            tile[i][sq + 4 * u + 0] = v.x; tile[i][sq + 4 * u + 1] = v.y;
            tile[i][sq + 4 * u + 2] = v.z; tile[i][sq + 4 * u + 3] = v.w;
        }
    }
    __syncthreads();
    {
        int s = t >> 2, jq = (t & 3) * 16;
        _Float16 hbuf[16], lbuf[16];
        #pragma unroll
        for (int u = 0; u < 16; u++) {
            float x = tile[jq + u][s];
            _Float16 hi = (_Float16)x;
            hbuf[u] = hi;
            lbuf[u] = (_Float16)(x - (float)hi);
        }
        size_t off = (size_t)hc * SS * DD + (size_t)s * DD + d0 + jq;
        *(half8*)(Wth + off)     = *(half8*)(hbuf);
        *(half8*)(Wth + off + 8) = *(half8*)(hbuf + 8);
        *(half8*)(Wtl + off)     = *(half8*)(lbuf);
        *(half8*)(Wtl + off + 8) = *(half8*)(lbuf + 8);
    }
}

// ---------------- Kernel 1: QKV projection, fp16x3 MFMA, SW-pipelined -------
// grid (48 hc, 32 token-tiles): same-hc blocks are ≡hc (mod 8) in dispatch
// order -> same XCD -> weight slab hot in that XCD's L2.
// Register double-buffer: A/B frags for k-step k+32 load during k's 48 MFMA.
__global__ __launch_bounds__(256, 2) void qkv_mfma(
    const _Float16* __restrict__ Xh, const _Float16* __restrict__ Xl,
    const _Float16* __restrict__ Wth, const _Float16* __restrict__ Wtl,
    _Float16* __restrict__ Qh, _Float16* __restrict__ Ql,
    _Float16* __restrict__ Kh, _Float16* __restrict__ Kl,
    _Float16* __restrict__ Vt)
{
    const int hc = blockIdx.x;
    const int h = hc / 3, c = hc % 3;
    const int lane = threadIdx.x & 63, wave = threadIdx.x >> 6;
    const int l16 = lane & 15, quad = lane >> 4;
    const int r0 = blockIdx.y * 256 + wave * 64;

    const _Float16* wb_h = Wth + (size_t)hc * SS * DD;
    const _Float16* wb_l = Wtl + (size_t)hc * SS * DD;

    floatx4 acc[4][4];
    #pragma unroll
    for (int i = 0; i < 4; i++)
        #pragma unroll
        for (int j = 0; j < 4; j++) acc[i][j] = (floatx4){0.f, 0.f, 0.f, 0.f};

    // frag buffers: A[0..3]=Ah, A[4..7]=Al ; B[0..3]=Bh, B[4..7]=Bl
    half8 A0[8], B0[8], A1[8], B1[8];

#define LOAD_A(Af, k0_) do {                                             \
    const int ka_ = (k0_) + 8 * quad;                                    \
    _Pragma("unroll")                                                    \
    for (int t = 0; t < 4; t++) {                                        \
        size_t arow = (size_t)(r0 + 16 * t + l16) * DD + ka_;            \
        Af[t]     = *(const half8*)(Xh + arow);                          \
        Af[4 + t] = *(const half8*)(Xl + arow);                          \
    } } while (0)

#define LOAD_B(Bf, k0_) do {                                             \
    const int ka_ = (k0_) + 8 * quad;                                    \
    _Pragma("unroll")                                                    \
    for (int t = 0; t < 4; t++) {                                        \
        size_t brow = (size_t)(16 * t + l16) * DD + ka_;                 \
        Bf[t]     = *(const half8*)(wb_h + brow);                        \
        Bf[4 + t] = *(const half8*)(wb_l + brow);                        \
    } } while (0)

#define MFMA_STEP(Af, Bf) do {                                           \
    _Pragma("unroll")                                                    \
    for (int i = 0; i < 4; i++)                                          \
        _Pragma("unroll")                                                \
        for (int j = 0; j < 4; j++)                                      \
            acc[i][j] = MFMA16(Af[i], Bf[j], acc[i][j]);                 \
    _Pragma("unroll")                                                    \
    for (int i = 0; i < 4; i++)                                          \
        _Pragma("unroll")                                                \
        for (int j = 0; j < 4; j++)                                      \
            acc[i][j] = MFMA16(Af[i], Bf[4 + j], acc[i][j]);             \
    _Pragma("unroll")                                                    \
    for (int i = 0; i < 4; i++)                                          \
        _Pragma("unroll")                                                \
        for (int j = 0; j < 4; j++)                                      \
            acc[i][j] = MFMA16(Af[4 + i], Bf[j], acc[i][j]);             \
    } while (0)

    LOAD_A(A0, 0); LOAD_B(B0, 0);
    for (int k0 = 0; k0 < DD; k0 += 64) {
        LOAD_A(A1, k0 + 32); LOAD_B(B1, k0 + 32);
        MFMA_STEP(A0, B0);
        if (k0 + 64 < DD) { LOAD_A(A0, k0 + 64); LOAD_B(B0, k0 + 64); }
        MFMA_STEP(A1, B1);
    }
#undef LOAD_A
#undef LOAD_B
#undef MFMA_STEP

    if (c == 2) {
        #pragma unroll
        for (int i = 0; i < 4; i++)
            #pragma unroll
            for (int j = 0; j < 4; j++) {
                int tok0 = r0 + 16 * i + 4 * quad;
                int b = tok0 >> 10, n0 = tok0 & 1023;
                half4v pk;
                #pragma unroll
                for (int r = 0; r < 4; r++) pk[r] = (_Float16)acc[i][j][r];
                *(half4v*)(Vt + ((size_t)(b * HH + h) * SS + 16 * j + l16) * NN + n0) = pk;
            }
    } else {
        _Float16* Ph = (c == 0) ? Qh : Kh;
        _Float16* Pl = (c == 0) ? Ql : Kl;
        #pragma unroll
        for (int i = 0; i < 4; i++)
            #pragma unroll
            for (int j = 0; j < 4; j++)
                #pragma unroll
                for (int r = 0; r < 4; r++) {
                    int tok = r0 + 16 * i + 4 * quad + r;
                    int b = tok >> 10, n = tok & 1023;
                    float v = acc[i][j][r];
                    _Float16 vh = (_Float16)v;
                    _Float16 vl = (_Float16)(v - (float)vh);
                    size_t off = ((size_t)(b * HH + h) * NN + n) * SS + 16 * j + l16;
                    Ph[off] = vh; Pl[off] = vl;
                }
    }
}

// ---------------- Kernel 2: MFMA flash attention, SW-pipelined --------------
// grid (128 bh, 16 qt): same-bh blocks ≡bh (mod 8) -> same XCD -> K/V L2-hot.
// Wave owns 16 q-rows. K frags double-buffered one tile ahead; V frags issued
// at body start (covered by S-MFMA + softmax). No __syncthreads in K-loop.
__global__ __launch_bounds__(256, 2) void attn_mfma(
    const _Float16* __restrict__ Qh, const _Float16* __restrict__ Ql,
    const _Float16* __restrict__ Kh, const _Float16* __restrict__ Kl,
    const _Float16* __restrict__ Vt,
    const float* __restrict__ mask,
    float* __restrict__ out)
{
    const int bh = blockIdx.x, qt = blockIdx.y;
    const int b = bh >> 4, h = bh & 15;
    const int tid = threadIdx.x;
    const int wave = tid >> 6, lane = tid & 63;
    const int l16 = lane & 15, quad = lane >> 4;

    __shared__ float Ms[NN];
    __shared__ _Float16 Plds[4][16][72];

    *(float4*)&Ms[tid * 4] = *(const float4*)(mask + b * NN + tid * 4);
    __syncthreads();

    const int qrow0 = qt * 64 + wave * 16;
    const size_t qbase = ((size_t)bh * NN + qrow0 + l16) * SS + quad * 8;
    half8 Aqh[2], Aql[2];
    Aqh[0] = *(const half8*)(Qh + qbase);
    Aqh[1] = *(const half8*)(Qh + qbase + 32);
    Aql[0] = *(const half8*)(Ql + qbase);
    Aql[1] = *(const half8*)(Ql + qbase + 32);

    float qm[4], m_old[4], l_sum[4];
    #pragma unroll
    for (int r = 0; r < 4; r++) {
        qm[r] = Ms[qrow0 + quad * 4 + r];
        m_old[r] = -3.0e38f;
        l_sum[r] = 0.f;
    }
    floatx4 accO[4];
    #pragma unroll
    for (int j = 0; j < 4; j++) accO[j] = (floatx4){0.f, 0.f, 0.f, 0.f};

    half8 K0[16], K1[16];

#define LOAD_K(Kb, kt_) do {                                                  \
    _Pragma("unroll")                                                         \
    for (int jt = 0; jt < 4; jt++) {                                          \
        const size_t kb = ((size_t)bh * NN + (kt_) * 64 + jt * 16 + l16) * SS \
                          + quad * 8;                                         \
        Kb[jt * 4 + 0] = *(const half8*)(Kh + kb);                            \
        Kb[jt * 4 + 1] = *(const half8*)(Kh + kb + 32);                       \
        Kb[jt * 4 + 2] = *(const half8*)(Kl + kb);                            \
        Kb[jt * 4 + 3] = *(const half8*)(Kl + kb + 32);                       \
    } } while (0)

    auto body = [&](int kt, const half8* Kb) {
        // prefetch V for this tile (consumed after softmax)
        half8 Vf[8];
        #pragma unroll
        for (int ks = 0; ks < 2; ks++)
            #pragma unroll
            for (int j = 0; j < 4; j++)
                Vf[ks * 4 + j] = *(const half8*)(Vt + ((size_t)bh * SS + j * 16 + l16) * NN
                                                 + kt * 64 + ks * 32 + quad * 8);

        // ---- S = Q K^T (fp16x3) ----
        floatx4 accS[4];
        #pragma unroll
        for (int jt = 0; jt < 4; jt++) accS[jt] = (floatx4){0.f, 0.f, 0.f, 0.f};
        #pragma unroll
        for (int jt = 0; jt < 4; jt++) {
            accS[jt] = MFMA16(Aqh[0], Kb[jt * 4 + 0], accS[jt]);
            accS[jt] = MFMA16(Aqh[1], Kb[jt * 4 + 1], accS[jt]);
            accS[jt] = MFMA16(Aqh[0], Kb[jt * 4 + 2], accS[jt]);
            accS[jt] = MFMA16(Aqh[1], Kb[jt * 4 + 3], accS[jt]);
            accS[jt] = MFMA16(Aql[0], Kb[jt * 4 + 0], accS[jt]);
            accS[jt] = MFMA16(Aql[1], Kb[jt * 4 + 1], accS[jt]);
        }
        // ---- literal fp32 mask penalty (preserves ref's ulp(1e8)=8 bins) ----
        float km[4];
        #pragma unroll
        for (int jt = 0; jt < 4; jt++) km[jt] = Ms[kt * 64 + jt * 16 + l16];
        #pragma unroll
        for (int jt = 0; jt < 4; jt++)
            #pragma unroll
            for (int r = 0; r < 4; r++)
                accS[jt][r] -= 1.0e8f * (1.0f - qm[r] * km[jt]);

        // ---- online softmax ----
        float alpha[4];
        #pragma unroll
        for (int r = 0; r < 4; r++) {
            float mt = fmaxf(fmaxf(accS[0][r], accS[1][r]), fmaxf(accS[2][r], accS[3][r]));
            #pragma unroll
            for (int off = 1; off < 16; off <<= 1)
                mt = fmaxf(mt, __shfl_xor(mt, off, 64));
            float mn = fmaxf(m_old[r], mt);
            alpha[r] = __expf(m_old[r] - mn);
            m_old[r] = mn;
            float ls = 0.f;
            #pragma unroll
            for (int jt = 0; jt < 4; jt++) {
                float pj = __expf(accS[jt][r] - mn);
                accS[jt][r] = pj;
                ls += pj;
            }
            #pragma unroll
            for (int off = 1; off < 16; off <<= 1)
                ls += __shfl_xor(ls, off, 64);
            l_sum[r] = l_sum[r] * alpha[r] + ls;
        }
        #pragma unroll
        for (int j = 0; j < 4; j++)
            #pragma unroll
            for (int r = 0; r < 4; r++)
                accO[j][r] *= alpha[r];

        // ---- P -> LDS (C/D -> A layout), XOR col-swizzle by row-quad ----
        #pragma unroll
        for (int jt = 0; jt < 4; jt++)
            #pragma unroll
            for (int r = 0; r < 4; r++)
                Plds[wave][quad * 4 + r][((jt ^ quad) << 4) + l16] = (_Float16)accS[jt][r];

        // ---- O += P V ----
        #pragma unroll
        for (int ks = 0; ks < 2; ks++) {
            int cbase = (((2 * ks + (quad >> 1)) ^ (l16 >> 2)) << 4) + (quad & 1) * 8;
            half8 Ap = *(const half8*)&Plds[wave][l16][cbase];
            #pragma unroll
            for (int j = 0; j < 4; j++)
                accO[j] = MFMA16(Ap, Vf[ks * 4 + j], accO[j]);
        }
    };

    LOAD_K(K0, 0);
    for (int kt = 0; kt < 16; kt += 2) {
        LOAD_K(K1, kt + 1);
        body(kt, K0);
        if (kt + 2 < 16) LOAD_K(K0, kt + 2);
        body(kt + 1, K1);
    }
#undef LOAD_K

    // ---- epilogue: out[b, n, s*16 + h] ----
    #pragma unroll
    for (int r = 0; r < 4; r++) {
        float inv = 1.f / l_sum[r];
        int qrow = qrow0 + quad * 4 + r;
        #pragma unroll
        for (int j = 0; j < 4; j++)
            out[((size_t)(b * NN + qrow)) * (SS * HH) + (j * 16 + l16) * HH + h] =
                accO[j][r] * inv;
    }
}

// ================= fp32 fallback path (R2, known-good) =================
__global__ __launch_bounds__(256) void qkv_kernel(
    const float* __restrict__ X, const float* __restrict__ W, float* __restrict__ qkv)
{
    const int ttile = blockIdx.x;
    const int hc    = blockIdx.y;
    const int h     = hc / 3, c = hc % 3;
    const int tid = threadIdx.x;
    const int tx = tid & 15, ty = tid >> 4;
    __shared__ float As[32][68];
    __shared__ float Bs[32][68];
    const float* Wb = W + (size_t)hc * DD * SS;
    const int row0 = ttile * 64;
    float acc[4][4];
    #pragma unroll
    for (int i = 0; i < 4; i++)
        #pragma unroll
        for (int j = 0; j < 4; j++) acc[i][j] = 0.f;
    for (int k0 = 0; k0 < DD; k0 += 32) {
        #pragma unroll
        for (int l = 0; l < 2; l++) {
            int i = tid + l * 256;
            int r = i >> 3;
            int kq = (i & 7) * 4;
            float4 x4 = *(const float4*)(X + (size_t)(row0 + r) * DD + k0 + kq);
            As[kq + 0][r] = x4.x; As[kq + 1][r] = x4.y;
            As[kq + 2][r] = x4.z; As[kq + 3][r] = x4.w;
        }
        #pragma unroll
        for (int l = 0; l < 2; l++) {
            int i = tid + l * 256;
            int kr = i >> 4;
            int sq = (i & 15) * 4;
            *(float4*)&Bs[kr][sq] = *(const float4*)(Wb + (size_t)(k0 + kr) * SS + sq);
        }
        __syncthreads();
        #pragma unroll
        for (int kk = 0; kk < 32; kk++) {
            float4 a4 = *(const float4*)&As[kk][ty * 4];
            float4 b4 = *(const float4*)&Bs[kk][tx * 4];
            float a[4] = {a4.x, a4.y, a4.z, a4.w};
            float bb[4] = {b4.x, b4.y, b4.z, b4.w};
            #pragma unroll
            for (int i = 0; i < 4; i++)
                #pragma unroll
                for (int j = 0; j < 4; j++)
                    acc[i][j] = fmaf(a[i], bb[j], acc[i][j]);
        }
        __syncthreads();
    }
    float* outp = qkv + (size_t)c * BH * NN * SS;
    #pragma unroll
    for (int i = 0; i < 4; i++) {
        int tg = row0 + ty * 4 + i;
        int b = tg >> 10, n = tg & 1023;
        float4 v4 = make_float4(acc[i][0], acc[i][1], acc[i][2], acc[i][3]);
        *(float4*)(outp + ((size_t)(b * HH + h) * NN + n) * SS + tx * 4) = v4;
    }
}

__global__ __launch_bounds__(256) void attn_kernel(
    const float* __restrict__ qkv,
    const float* __restrict__ mask,
    float* __restrict__ out)
{
    const int qt = blockIdx.x, h = blockIdx.y, b = blockIdx.z;
    const int tid = threadIdx.x;
    const int tx = tid & 15, ty = tid >> 4;
    const int bh = b * HH + h;
    const float* Q = qkv + (size_t)bh * NN * SS;
    const float* K = qkv + (size_t)BH * NN * SS + (size_t)bh * NN * SS;
    const float* V = qkv + 2 * (size_t)BH * NN * SS + (size_t)bh * NN * SS;

    __shared__ float QsT[64][68];
    __shared__ float KsT[64][68];
    __shared__ float Vs [64][68];
    __shared__ float PsT[64][68];
    __shared__ float Ms[NN];

    {
        float4 mm = *(const float4*)(mask + b * NN + tid * 4);
        *(float4*)&Ms[tid * 4] = mm;
    }
    #pragma unroll
    for (int l = 0; l < 4; l++) {
        int i = tid + l * 256;
        int r = i >> 4, sq = (i & 15) * 4;
        float4 x4 = *(const float4*)(Q + (size_t)(qt * 64 + r) * SS + sq);
        QsT[sq + 0][r] = x4.x; QsT[sq + 1][r] = x4.y;
        QsT[sq + 2][r] = x4.z; QsT[sq + 3][r] = x4.w;
    }
    __syncthreads();

    float m_old[4], l_sum[4], O[4][4], qm[4];
    #pragma unroll
    for (int i = 0; i < 4; i++) {
        qm[i] = Ms[qt * 64 + ty * 4 + i];
        m_old[i] = -3.0e38f; l_sum[i] = 0.f;
        #pragma unroll
        for (int j = 0; j < 4; j++) O[i][j] = 0.f;
    }

    for (int kt = 0; kt < 16; kt++) {
        #pragma unroll
        for (int l = 0; l < 4; l++) {
            int i = tid + l * 256;
            int r = i >> 4, sq = (i & 15) * 4;
            float4 k4 = *(const float4*)(K + (size_t)(kt * 64 + r) * SS + sq);
            KsT[sq + 0][r] = k4.x; KsT[sq + 1][r] = k4.y;
            KsT[sq + 2][r] = k4.z; KsT[sq + 3][r] = k4.w;
            float4 v4 = *(const float4*)(V + (size_t)(kt * 64 + r) * SS + sq);
            *(float4*)&Vs[r][sq] = v4;
        }
        __syncthreads();

        float sc[4][4];
        #pragma unroll
        for (int i = 0; i < 4; i++)
            #pragma unroll
            for (int j = 0; j < 4; j++) sc[i][j] = 0.f;
        #pragma unroll 8
        for (int s = 0; s < 64; s++) {
            float4 a4 = *(const float4*)&QsT[s][ty * 4];
            float4 b4 = *(const float4*)&KsT[s][tx * 4];
            float a[4] = {a4.x, a4.y, a4.z, a4.w};
            float bb[4] = {b4.x, b4.y, b4.z, b4.w};
            #pragma unroll
            for (int i = 0; i < 4; i++)
                #pragma unroll
                for (int j = 0; j < 4; j++)
                    sc[i][j] = fmaf(a[i], bb[j], sc[i][j]);
        }
        float km[4];
        #pragma unroll
        for (int j = 0; j < 4; j++) km[j] = Ms[kt * 64 + tx * 4 + j];
        #pragma unroll
        for (int i = 0; i < 4; i++)
            #pragma unroll
            for (int j = 0; j < 4; j++) {
                float pen = 1.0e8f * (1.0f - qm[i] * km[j]);
                sc[i][j] = sc[i][j] - pen;
            }

        #pragma unroll
        for (int i = 0; i < 4; i++) {
            float mt = fmaxf(fmaxf(sc[i][0], sc[i][1]), fmaxf(sc[i][2], sc[i][3]));
            #pragma unroll
            for (int off = 1; off < 16; off <<= 1)
                mt = fmaxf(mt, __shfl_xor(mt, off, 64));
            float mn = fmaxf(m_old[i], mt);
            float alpha = __expf(m_old[i] - mn);
            float p[4];
            #pragma unroll
            for (int j = 0; j < 4; j++) p[j] = __expf(sc[i][j] - mn);
            float ls = (p[0] + p[1]) + (p[2] + p[3]);
            #pragma unroll
            for (int off = 1; off < 16; off <<= 1)
                ls += __shfl_xor(ls, off, 64);
            l_sum[i] = l_sum[i] * alpha + ls;
            m_old[i] = mn;
            #pragma unroll
            for (int j = 0; j < 4; j++) {
                O[i][j] *= alpha;
                PsT[tx * 4 + j][ty * 4 + i] = p[j];
            }
        }
        __syncthreads();

        #pragma unroll 8
        for (int kj = 0; kj < 64; kj++) {
            float4 p4 = *(const float4*)&PsT[kj][ty * 4];
            float4 v4 = *(const float4*)&Vs[kj][tx * 4];
            float p[4] = {p4.x, p4.y, p4.z, p4.w};
            float vv[4] = {v4.x, v4.y, v4.z, v4.w};
            #pragma unroll
            for (int i = 0; i < 4; i++)
                #pragma unroll
                for (int j = 0; j < 4; j++)
                    O[i][j] = fmaf(p[i], vv[j], O[i][j]);
        }
        __syncthreads();
    }

    #pragma unroll
    for (int i = 0; i < 4; i++) {
        int qrow = qt * 64 + ty * 4 + i;
        float inv = 1.f / l_sum[i];
        #pragma unroll
        for (int j = 0; j < 4; j++) {
            int s = tx * 4 + j;
            out[((size_t)(b * NN + qrow)) * (SS * HH) + s * HH + h] = O[i][j] * inv;
        }
    }
}

extern "C" void kernel_launch(void* const* d_in, const int* in_sizes, int n_in,
                              void* d_out, int out_size, void* d_ws, size_t ws_size,
                              hipStream_t stream) {
    const float* X    = (const float*)d_in[0];   // [8,1024,1024]
    const float* mask = (const float*)d_in[1];   // [8,1024]
    const float* W    = (const float*)d_in[2];   // [16,3,1024,64]
    float* out = (float*)d_out;

    const size_t x_elems  = (size_t)BB * NN * DD;       // 8,388,608
    const size_t w_elems  = (size_t)HH * 3 * SS * DD;   // 3,145,728
    const size_t qk_elems = (size_t)BH * NN * SS;       // 8,388,608
    const size_t need_fast = (2 * x_elems + 2 * w_elems + 5 * qk_elems) * sizeof(_Float16); // ~130 MB

    if (ws_size >= need_fast) {
        _Float16* Xh  = (_Float16*)d_ws;
        _Float16* Xl  = Xh  + x_elems;
        _Float16* Wth = Xl  + x_elems;
        _Float16* Wtl = Wth + w_elems;
        _Float16* Qh  = Wtl + w_elems;
        _Float16* Ql  = Qh  + qk_elems;
        _Float16* Kh  = Ql  + qk_elems;
        _Float16* Kl  = Kh  + qk_elems;
        _Float16* Vt  = Kl  + qk_elems;

        split_x<<<dim3((unsigned)(x_elems / 1024)), dim3(256), 0, stream>>>(X, Xh, Xl);
        split_wt<<<dim3(48, 16), dim3(256), 0, stream>>>(W, Wth, Wtl);
        qkv_mfma<<<dim3(48, 32), dim3(256), 0, stream>>>(Xh, Xl, Wth, Wtl, Qh, Ql, Kh, Kl, Vt);
        attn_mfma<<<dim3(128, 16), dim3(256), 0, stream>>>(Qh, Ql, Kh, Kl, Vt, mask, out);
    } else if (ws_size >= 3ull * BH * NN * SS * sizeof(float)) {
        float* qkv = (float*)d_ws;
        qkv_kernel<<<dim3(128, 48), dim3(256), 0, stream>>>(X, W, qkv);
        attn_kernel<<<dim3(16, 16, 8), dim3(256), 0, stream>>>(qkv, mask, out);
    }
}

// Round 7
// 783.083 us; speedup vs baseline: 1.0552x; 1.0552x over previous
//
#include <hip/hip_runtime.h>
#include <math.h>

#define BB 8
#define NN 1024
#define DD 1024
#define HH 16
#define SS 64
#define BH (BB*HH)

typedef _Float16 half8 __attribute__((ext_vector_type(8)));
typedef _Float16 half4v __attribute__((ext_vector_type(4)));
typedef float floatx4 __attribute__((ext_vector_type(4)));

#define MFMA16(A, B, C) __builtin_amdgcn_mfma_f32_16x16x32_f16((A), (B), (C), 0, 0, 0)

// ---------------- Pre-pass: split X into fp16 hi/lo ----------------
__global__ __launch_bounds__(256) void split_x(
    const float* __restrict__ X, _Float16* __restrict__ Xh, _Float16* __restrict__ Xl)
{
    int idx = (blockIdx.x * 256 + threadIdx.x) * 4;
    float4 x4 = *(const float4*)(X + idx);
    float xs[4] = {x4.x, x4.y, x4.z, x4.w};
    half4v h, l;
    #pragma unroll
    for (int i = 0; i < 4; i++) {
        _Float16 hi = (_Float16)xs[i];
        h[i] = hi;
        l[i] = (_Float16)(xs[i] - (float)hi);
    }
    *(half4v*)(Xh + idx) = h;
    *(half4v*)(Xl + idx) = l;
}

// ---------------- Pre-pass: split + transpose W ----------------
__global__ __launch_bounds__(256) void split_wt(
    const float* __restrict__ W, _Float16* __restrict__ Wth, _Float16* __restrict__ Wtl)
{
    __shared__ float tile[64][68];
    const int hc = blockIdx.x, d0 = blockIdx.y * 64;
    const int t = threadIdx.x;
    {
        int i = t >> 2, sq = (t & 3) * 16;
        const float* src = W + ((size_t)hc * DD + d0 + i) * SS + sq;
        #pragma unroll
        for (int u = 0; u < 4; u++) {
            float4 v = *(const float4*)(src + 4 * u);
            tile[i][sq + 4 * u + 0] = v.x; tile[i][sq + 4 * u + 1] = v.y;
            tile[i][sq + 4 * u + 2] = v.z; tile[i][sq + 4 * u + 3] = v.w;
        }
    }
    __syncthreads();
    {
        int s = t >> 2, jq = (t & 3) * 16;
        _Float16 hbuf[16], lbuf[16];
        #pragma unroll
        for (int u = 0; u < 16; u++) {
            float x = tile[jq + u][s];
            _Float16 hi = (_Float16)x;
            hbuf[u] = hi;
            lbuf[u] = (_Float16)(x - (float)hi);
        }
        size_t off = (size_t)hc * SS * DD + (size_t)s * DD + d0 + jq;
        *(half8*)(Wth + off)     = *(half8*)(hbuf);
        *(half8*)(Wth + off + 8) = *(half8*)(hbuf + 8);
        *(half8*)(Wtl + off)     = *(half8*)(lbuf);
        *(half8*)(Wtl + off + 8) = *(half8*)(lbuf + 8);
    }
}

// ---------------- Kernel 1: QKV projection, fp16x3 MFMA, hc-PAIR per block --
// grid (24 hc-pair, 32 token-tiles): same-pair blocks have linear id ≡ x
// (mod 8) -> same XCD -> 512 KB weight slab L2-hot. A-frags loaded once per
// k-step feed both hc's 96 MFMA (known-good R5 structure, no reg pressure).
__global__ __launch_bounds__(256, 2) void qkv_mfma(
    const _Float16* __restrict__ Xh, const _Float16* __restrict__ Xl,
    const _Float16* __restrict__ Wth, const _Float16* __restrict__ Wtl,
    _Float16* __restrict__ Qh, _Float16* __restrict__ Ql,
    _Float16* __restrict__ Kh, _Float16* __restrict__ Kl,
    _Float16* __restrict__ Vt)
{
    const int hc0 = blockIdx.x * 2;
    const int lane = threadIdx.x & 63, wave = threadIdx.x >> 6;
    const int l16 = lane & 15, quad = lane >> 4;
    const int r0 = blockIdx.y * 256 + wave * 64;

    floatx4 acc[2][4][4];
    #pragma unroll
    for (int p = 0; p < 2; p++)
        #pragma unroll
        for (int i = 0; i < 4; i++)
            #pragma unroll
            for (int j = 0; j < 4; j++) acc[p][i][j] = (floatx4){0.f, 0.f, 0.f, 0.f};

    for (int k0 = 0; k0 < DD; k0 += 32) {
        const int ka = k0 + 8 * quad;
        half8 Ah[4], Al[4];
        #pragma unroll
        for (int t = 0; t < 4; t++) {
            size_t arow = (size_t)(r0 + 16 * t + l16) * DD + ka;
            Ah[t] = *(const half8*)(Xh + arow);
            Al[t] = *(const half8*)(Xl + arow);
        }
        #pragma unroll
        for (int p = 0; p < 2; p++) {
            const _Float16* wb_h = Wth + (size_t)(hc0 + p) * SS * DD;
            const _Float16* wb_l = Wtl + (size_t)(hc0 + p) * SS * DD;
            half8 Bh[4], Bl[4];
            #pragma unroll
            for (int t = 0; t < 4; t++) {
                size_t brow = (size_t)(16 * t + l16) * DD + ka;
                Bh[t] = *(const half8*)(wb_h + brow);
                Bl[t] = *(const half8*)(wb_l + brow);
            }
            #pragma unroll
            for (int i = 0; i < 4; i++)
                #pragma unroll
                for (int j = 0; j < 4; j++)
                    acc[p][i][j] = MFMA16(Ah[i], Bh[j], acc[p][i][j]);
            #pragma unroll
            for (int i = 0; i < 4; i++)
                #pragma unroll
                for (int j = 0; j < 4; j++)
                    acc[p][i][j] = MFMA16(Ah[i], Bl[j], acc[p][i][j]);
            #pragma unroll
            for (int i = 0; i < 4; i++)
                #pragma unroll
                for (int j = 0; j < 4; j++)
                    acc[p][i][j] = MFMA16(Al[i], Bh[j], acc[p][i][j]);
        }
    }

    #pragma unroll
    for (int p = 0; p < 2; p++) {
        const int hc = hc0 + p;
        const int h = hc / 3, c = hc % 3;
        if (c == 2) {
            #pragma unroll
            for (int i = 0; i < 4; i++)
                #pragma unroll
                for (int j = 0; j < 4; j++) {
                    int tok0 = r0 + 16 * i + 4 * quad;
                    int b = tok0 >> 10, n0 = tok0 & 1023;
                    half4v pk;
                    #pragma unroll
                    for (int r = 0; r < 4; r++) pk[r] = (_Float16)acc[p][i][j][r];
                    *(half4v*)(Vt + ((size_t)(b * HH + h) * SS + 16 * j + l16) * NN + n0) = pk;
                }
        } else {
            _Float16* Ph = (c == 0) ? Qh : Kh;
            _Float16* Pl = (c == 0) ? Ql : Kl;
            #pragma unroll
            for (int i = 0; i < 4; i++)
                #pragma unroll
                for (int j = 0; j < 4; j++)
                    #pragma unroll
                    for (int r = 0; r < 4; r++) {
                        int tok = r0 + 16 * i + 4 * quad + r;
                        int b = tok >> 10, n = tok & 1023;
                        float v = acc[p][i][j][r];
                        _Float16 vh = (_Float16)v;
                        _Float16 vl = (_Float16)(v - (float)vh);
                        size_t off = ((size_t)(b * HH + h) * NN + n) * SS + 16 * j + l16;
                        Ph[off] = vh; Pl[off] = vl;
                    }
        }
    }
}

// ---------------- Kernel 2: MFMA flash attention, SW-pipelined --------------
// grid (128 bh, 16 qt): same-bh blocks ≡ bh (mod 8) -> same XCD -> K/V L2-hot.
// Wave owns 16 q-rows. K frags double-buffered one tile ahead; V frags issued
// at body start. __launch_bounds__(256,1): 512-VGPR cap so the ~280-reg
// pipeline does NOT spill (R6's (256,2) cap caused 280 MB of scratch stores).
__global__ __launch_bounds__(256, 1) void attn_mfma(
    const _Float16* __restrict__ Qh, const _Float16* __restrict__ Ql,
    const _Float16* __restrict__ Kh, const _Float16* __restrict__ Kl,
    const _Float16* __restrict__ Vt,
    const float* __restrict__ mask,
    float* __restrict__ out)
{
    const int bh = blockIdx.x, qt = blockIdx.y;
    const int b = bh >> 4, h = bh & 15;
    const int tid = threadIdx.x;
    const int wave = tid >> 6, lane = tid & 63;
    const int l16 = lane & 15, quad = lane >> 4;

    __shared__ float Ms[NN];
    __shared__ _Float16 Plds[4][16][72];

    *(float4*)&Ms[tid * 4] = *(const float4*)(mask + b * NN + tid * 4);
    __syncthreads();

    const int qrow0 = qt * 64 + wave * 16;
    const size_t qbase = ((size_t)bh * NN + qrow0 + l16) * SS + quad * 8;
    half8 Aqh[2], Aql[2];
    Aqh[0] = *(const half8*)(Qh + qbase);
    Aqh[1] = *(const half8*)(Qh + qbase + 32);
    Aql[0] = *(const half8*)(Ql + qbase);
    Aql[1] = *(const half8*)(Ql + qbase + 32);

    float qm[4], m_old[4], l_sum[4];
    #pragma unroll
    for (int r = 0; r < 4; r++) {
        qm[r] = Ms[qrow0 + quad * 4 + r];
        m_old[r] = -3.0e38f;
        l_sum[r] = 0.f;
    }
    floatx4 accO[4];
    #pragma unroll
    for (int j = 0; j < 4; j++) accO[j] = (floatx4){0.f, 0.f, 0.f, 0.f};

    half8 K0[16], K1[16];

#define LOAD_K(Kb, kt_) do {                                                  \
    _Pragma("unroll")                                                         \
    for (int jt = 0; jt < 4; jt++) {                                          \
        const size_t kb = ((size_t)bh * NN + (kt_) * 64 + jt * 16 + l16) * SS \
                          + quad * 8;                                         \
        Kb[jt * 4 + 0] = *(const half8*)(Kh + kb);                            \
        Kb[jt * 4 + 1] = *(const half8*)(Kh + kb + 32);                       \
        Kb[jt * 4 + 2] = *(const half8*)(Kl + kb);                            \
        Kb[jt * 4 + 3] = *(const half8*)(Kl + kb + 32);                       \
    } } while (0)

    auto body = [&](int kt, const half8* Kb) {
        // prefetch V for this tile (consumed after softmax)
        half8 Vf[8];
        #pragma unroll
        for (int ks = 0; ks < 2; ks++)
            #pragma unroll
            for (int j = 0; j < 4; j++)
                Vf[ks * 4 + j] = *(const half8*)(Vt + ((size_t)bh * SS + j * 16 + l16) * NN
                                                 + kt * 64 + ks * 32 + quad * 8);

        // ---- S = Q K^T (fp16x3) ----
        floatx4 accS[4];
        #pragma unroll
        for (int jt = 0; jt < 4; jt++) accS[jt] = (floatx4){0.f, 0.f, 0.f, 0.f};
        #pragma unroll
        for (int jt = 0; jt < 4; jt++) {
            accS[jt] = MFMA16(Aqh[0], Kb[jt * 4 + 0], accS[jt]);
            accS[jt] = MFMA16(Aqh[1], Kb[jt * 4 + 1], accS[jt]);
            accS[jt] = MFMA16(Aqh[0], Kb[jt * 4 + 2], accS[jt]);
            accS[jt] = MFMA16(Aqh[1], Kb[jt * 4 + 3], accS[jt]);
            accS[jt] = MFMA16(Aql[0], Kb[jt * 4 + 0], accS[jt]);
            accS[jt] = MFMA16(Aql[1], Kb[jt * 4 + 1], accS[jt]);
        }
        // ---- literal fp32 mask penalty (preserves ref's ulp(1e8)=8 bins) ----
        float km[4];
        #pragma unroll
        for (int jt = 0; jt < 4; jt++) km[jt] = Ms[kt * 64 + jt * 16 + l16];
        #pragma unroll
        for (int jt = 0; jt < 4; jt++)
            #pragma unroll
            for (int r = 0; r < 4; r++)
                accS[jt][r] -= 1.0e8f * (1.0f - qm[r] * km[jt]);

        // ---- online softmax ----
        float alpha[4];
        #pragma unroll
        for (int r = 0; r < 4; r++) {
            float mt = fmaxf(fmaxf(accS[0][r], accS[1][r]), fmaxf(accS[2][r], accS[3][r]));
            #pragma unroll
            for (int off = 1; off < 16; off <<= 1)
                mt = fmaxf(mt, __shfl_xor(mt, off, 64));
            float mn = fmaxf(m_old[r], mt);
            alpha[r] = __expf(m_old[r] - mn);
            m_old[r] = mn;
            float ls = 0.f;
            #pragma unroll
            for (int jt = 0; jt < 4; jt++) {
                float pj = __expf(accS[jt][r] - mn);
                accS[jt][r] = pj;
                ls += pj;
            }
            #pragma unroll
            for (int off = 1; off < 16; off <<= 1)
                ls += __shfl_xor(ls, off, 64);
            l_sum[r] = l_sum[r] * alpha[r] + ls;
        }
        #pragma unroll
        for (int j = 0; j < 4; j++)
            #pragma unroll
            for (int r = 0; r < 4; r++)
                accO[j][r] *= alpha[r];

        // ---- P -> LDS (C/D -> A layout), XOR col-swizzle by row-quad ----
        #pragma unroll
        for (int jt = 0; jt < 4; jt++)
            #pragma unroll
            for (int r = 0; r < 4; r++)
                Plds[wave][quad * 4 + r][((jt ^ quad) << 4) + l16] = (_Float16)accS[jt][r];

        // ---- O += P V ----
        #pragma unroll
        for (int ks = 0; ks < 2; ks++) {
            int cbase = (((2 * ks + (quad >> 1)) ^ (l16 >> 2)) << 4) + (quad & 1) * 8;
            half8 Ap = *(const half8*)&Plds[wave][l16][cbase];
            #pragma unroll
            for (int j = 0; j < 4; j++)
                accO[j] = MFMA16(Ap, Vf[ks * 4 + j], accO[j]);
        }
    };

    LOAD_K(K0, 0);
    for (int kt = 0; kt < 16; kt += 2) {
        LOAD_K(K1, kt + 1);
        body(kt, K0);
        if (kt + 2 < 16) LOAD_K(K0, kt + 2);
        body(kt + 1, K1);
    }
#undef LOAD_K

    // ---- epilogue: out[b, n, s*16 + h] ----
    #pragma unroll
    for (int r = 0; r < 4; r++) {
        float inv = 1.f / l_sum[r];
        int qrow = qrow0 + quad * 4 + r;
        #pragma unroll
        for (int j = 0; j < 4; j++)
            out[((size_t)(b * NN + qrow)) * (SS * HH) + (j * 16 + l16) * HH + h] =
                accO[j][r] * inv;
    }
}

// ================= fp32 fallback path (R2, known-good) =================
__global__ __launch_bounds__(256) void qkv_kernel(
    const float* __restrict__ X, const float* __restrict__ W, float* __restrict__ qkv)
{
    const int ttile = blockIdx.x;
    const int hc    = blockIdx.y;
    const int h     = hc / 3, c = hc % 3;
    const int tid = threadIdx.x;
    const int tx = tid & 15, ty = tid >> 4;
    __shared__ float As[32][68];
    __shared__ float Bs[32][68];
    const float* Wb = W + (size_t)hc * DD * SS;
    const int row0 = ttile * 64;
    float acc[4][4];
    #pragma unroll
    for (int i = 0; i < 4; i++)
        #pragma unroll
        for (int j = 0; j < 4; j++) acc[i][j] = 0.f;
    for (int k0 = 0; k0 < DD; k0 += 32) {
        #pragma unroll
        for (int l = 0; l < 2; l++) {
            int i = tid + l * 256;
            int r = i >> 3;
            int kq = (i & 7) * 4;
            float4 x4 = *(const float4*)(X + (size_t)(row0 + r) * DD + k0 + kq);
            As[kq + 0][r] = x4.x; As[kq + 1][r] = x4.y;
            As[kq + 2][r] = x4.z; As[kq + 3][r] = x4.w;
        }
        #pragma unroll
        for (int l = 0; l < 2; l++) {
            int i = tid + l * 256;
            int kr = i >> 4;
            int sq = (i & 15) * 4;
            *(float4*)&Bs[kr][sq] = *(const float4*)(Wb + (size_t)(k0 + kr) * SS + sq);
        }
        __syncthreads();
        #pragma unroll
        for (int kk = 0; kk < 32; kk++) {
            float4 a4 = *(const float4*)&As[kk][ty * 4];
            float4 b4 = *(const float4*)&Bs[kk][tx * 4];
            float a[4] = {a4.x, a4.y, a4.z, a4.w};
            float bb[4] = {b4.x, b4.y, b4.z, b4.w};
            #pragma unroll
            for (int i = 0; i < 4; i++)
                #pragma unroll
                for (int j = 0; j < 4; j++)
                    acc[i][j] = fmaf(a[i], bb[j], acc[i][j]);
        }
        __syncthreads();
    }
    float* outp = qkv + (size_t)c * BH * NN * SS;
    #pragma unroll
    for (int i = 0; i < 4; i++) {
        int tg = row0 + ty * 4 + i;
        int b = tg >> 10, n = tg & 1023;
        float4 v4 = make_float4(acc[i][0], acc[i][1], acc[i][2], acc[i][3]);
        *(float4*)(outp + ((size_t)(b * HH + h) * NN + n) * SS + tx * 4) = v4;
    }
}

__global__ __launch_bounds__(256) void attn_kernel(
    const float* __restrict__ qkv,
    const float* __restrict__ mask,
    float* __restrict__ out)
{
    const int qt = blockIdx.x, h = blockIdx.y, b = blockIdx.z;
    const int tid = threadIdx.x;
    const int tx = tid & 15, ty = tid >> 4;
    const int bh = b * HH + h;
    const float* Q = qkv + (size_t)bh * NN * SS;
    const float* K = qkv + (size_t)BH * NN * SS + (size_t)bh * NN * SS;
    const float* V = qkv + 2 * (size_t)BH * NN * SS + (size_t)bh * NN * SS;

    __shared__ float QsT[64][68];
    __shared__ float KsT[64][68];
    __shared__ float Vs [64][68];
    __shared__ float PsT[64][68];
    __shared__ float Ms[NN];

    {
        float4 mm = *(const float4*)(mask + b * NN + tid * 4);
        *(float4*)&Ms[tid * 4] = mm;
    }
    #pragma unroll
    for (int l = 0; l < 4; l++) {
        int i = tid + l * 256;
        int r = i >> 4, sq = (i & 15) * 4;
        float4 x4 = *(const float4*)(Q + (size_t)(qt * 64 + r) * SS + sq);
        QsT[sq + 0][r] = x4.x; QsT[sq + 1][r] = x4.y;
        QsT[sq + 2][r] = x4.z; QsT[sq + 3][r] = x4.w;
    }
    __syncthreads();

    float m_old[4], l_sum[4], O[4][4], qm[4];
    #pragma unroll
    for (int i = 0; i < 4; i++) {
        qm[i] = Ms[qt * 64 + ty * 4 + i];
        m_old[i] = -3.0e38f; l_sum[i] = 0.f;
        #pragma unroll
        for (int j = 0; j < 4; j++) O[i][j] = 0.f;
    }

    for (int kt = 0; kt < 16; kt++) {
        #pragma unroll
        for (int l = 0; l < 4; l++) {
            int i = tid + l * 256;
            int r = i >> 4, sq = (i & 15) * 4;
            float4 k4 = *(const float4*)(K + (size_t)(kt * 64 + r) * SS + sq);
            KsT[sq + 0][r] = k4.x; KsT[sq + 1][r] = k4.y;
            KsT[sq + 2][r] = k4.z; KsT[sq + 3][r] = k4.w;
            float4 v4 = *(const float4*)(V + (size_t)(kt * 64 + r) * SS + sq);
            *(float4*)&Vs[r][sq] = v4;
        }
        __syncthreads();

        float sc[4][4];
        #pragma unroll
        for (int i = 0; i < 4; i++)
            #pragma unroll
            for (int j = 0; j < 4; j++) sc[i][j] = 0.f;
        #pragma unroll 8
        for (int s = 0; s < 64; s++) {
            float4 a4 = *(const float4*)&QsT[s][ty * 4];
            float4 b4 = *(const float4*)&KsT[s][tx * 4];
            float a[4] = {a4.x, a4.y, a4.z, a4.w};
            float bb[4] = {b4.x, b4.y, b4.z, b4.w};
            #pragma unroll
            for (int i = 0; i < 4; i++)
                #pragma unroll
                for (int j = 0; j < 4; j++)
                    sc[i][j] = fmaf(a[i], bb[j], sc[i][j]);
        }
        float km[4];
        #pragma unroll
        for (int j = 0; j < 4; j++) km[j] = Ms[kt * 64 + tx * 4 + j];
        #pragma unroll
        for (int i = 0; i < 4; i++)
            #pragma unroll
            for (int j = 0; j < 4; j++) {
                float pen = 1.0e8f * (1.0f - qm[i] * km[j]);
                sc[i][j] = sc[i][j] - pen;
            }

        #pragma unroll
        for (int i = 0; i < 4; i++) {
            float mt = fmaxf(fmaxf(sc[i][0], sc[i][1]), fmaxf(sc[i][2], sc[i][3]));
            #pragma unroll
            for (int off = 1; off < 16; off <<= 1)
                mt = fmaxf(mt, __shfl_xor(mt, off, 64));
            float mn = fmaxf(m_old[i], mt);
            float alpha = __expf(m_old[i] - mn);
            float p[4];
            #pragma unroll
            for (int j = 0; j < 4; j++) p[j] = __expf(sc[i][j] - mn);
            float ls = (p[0] + p[1]) + (p[2] + p[3]);
            #pragma unroll
            for (int off = 1; off < 16; off <<= 1)
                ls += __shfl_xor(ls, off, 64);
            l_sum[i] = l_sum[i] * alpha + ls;
            m_old[i] = mn;
            #pragma unroll
            for (int j = 0; j < 4; j++) {
                O[i][j] *= alpha;
                PsT[tx * 4 + j][ty * 4 + i] = p[j];
            }
        }
        __syncthreads();

        #pragma unroll 8
        for (int kj = 0; kj < 64; kj++) {
            float4 p4 = *(const float4*)&PsT[kj][ty * 4];
            float4 v4 = *(const float4*)&Vs[kj][tx * 4];
            float p[4] = {p4.x, p4.y, p4.z, p4.w};
            float vv[4] = {v4.x, v4.y, v4.z, v4.w};
            #pragma unroll
            for (int i = 0; i < 4; i++)
                #pragma unroll
                for (int j = 0; j < 4; j++)
                    O[i][j] = fmaf(p[i], vv[j], O[i][j]);
        }
        __syncthreads();
    }

    #pragma unroll
    for (int i = 0; i < 4; i++) {
        int qrow = qt * 64 + ty * 4 + i;
        float inv = 1.f / l_sum[i];
        #pragma unroll
        for (int j = 0; j < 4; j++) {
            int s = tx * 4 + j;
            out[((size_t)(b * NN + qrow)) * (SS * HH) + s * HH + h] = O[i][j] * inv;
        }
    }
}

extern "C" void kernel_launch(void* const* d_in, const int* in_sizes, int n_in,
                              void* d_out, int out_size, void* d_ws, size_t ws_size,
                              hipStream_t stream) {
    const float* X    = (const float*)d_in[0];   // [8,1024,1024]
    const float* mask = (const float*)d_in[1];   // [8,1024]
    const float* W    = (const float*)d_in[2];   // [16,3,1024,64]
    float* out = (float*)d_out;

    const size_t x_elems  = (size_t)BB * NN * DD;       // 8,388,608
    const size_t w_elems  = (size_t)HH * 3 * SS * DD;   // 3,145,728
    const size_t qk_elems = (size_t)BH * NN * SS;       // 8,388,608
    const size_t need_fast = (2 * x_elems + 2 * w_elems + 5 * qk_elems) * sizeof(_Float16); // ~130 MB

    if (ws_size >= need_fast) {
        _Float16* Xh  = (_Float16*)d_ws;
        _Float16* Xl  = Xh  + x_elems;
        _Float16* Wth = Xl  + x_elems;
        _Float16* Wtl = Wth + w_elems;
        _Float16* Qh  = Wtl + w_elems;
        _Float16* Ql  = Qh  + qk_elems;
        _Float16* Kh  = Ql  + qk_elems;
        _Float16* Kl  = Kh  + qk_elems;
        _Float16* Vt  = Kl  + qk_elems;

        split_x<<<dim3((unsigned)(x_elems / 1024)), dim3(256), 0, stream>>>(X, Xh, Xl);
        split_wt<<<dim3(48, 16), dim3(256), 0, stream>>>(W, Wth, Wtl);
        qkv_mfma<<<dim3(24, 32), dim3(256), 0, stream>>>(Xh, Xl, Wth, Wtl, Qh, Ql, Kh, Kl, Vt);
        attn_mfma<<<dim3(128, 16), dim3(256), 0, stream>>>(Qh, Ql, Kh, Kl, Vt, mask, out);
    } else if (ws_size >= 3ull * BH * NN * SS * sizeof(float)) {
        float* qkv = (float*)d_ws;
        qkv_kernel<<<dim3(128, 48), dim3(256), 0, stream>>>(X, W, qkv);
        attn_kernel<<<dim3(16, 16, 8), dim3(256), 0, stream>>>(qkv, mask, out);
    }
}

// Round 8
// 559.897 us; speedup vs baseline: 1.4758x; 1.3986x over previous
//
#include <hip/hip_runtime.h>
#include <math.h>

#define BB 8
#define NN 1024
#define DD 1024
#define HH 16
#define SS 64
#define BH (BB*HH)

typedef _Float16 half8 __attribute__((ext_vector_type(8)));
typedef _Float16 half4v __attribute__((ext_vector_type(4)));
typedef float floatx4 __attribute__((ext_vector_type(4)));

#define MFMA16(A, B, C) __builtin_amdgcn_mfma_f32_16x16x32_f16((A), (B), (C), 0, 0, 0)

// ---------------- Pre-pass: split X into fp16 hi/lo ----------------
__global__ __launch_bounds__(256) void split_x(
    const float* __restrict__ X, _Float16* __restrict__ Xh, _Float16* __restrict__ Xl)
{
    int idx = (blockIdx.x * 256 + threadIdx.x) * 4;
    float4 x4 = *(const float4*)(X + idx);
    float xs[4] = {x4.x, x4.y, x4.z, x4.w};
    half4v h, l;
    #pragma unroll
    for (int i = 0; i < 4; i++) {
        _Float16 hi = (_Float16)xs[i];
        h[i] = hi;
        l[i] = (_Float16)(xs[i] - (float)hi);
    }
    *(half4v*)(Xh + idx) = h;
    *(half4v*)(Xl + idx) = l;
}

// ---------------- Pre-pass: split + transpose W ----------------
__global__ __launch_bounds__(256) void split_wt(
    const float* __restrict__ W, _Float16* __restrict__ Wth, _Float16* __restrict__ Wtl)
{
    __shared__ float tile[64][68];
    const int hc = blockIdx.x, d0 = blockIdx.y * 64;
    const int t = threadIdx.x;
    {
        int i = t >> 2, sq = (t & 3) * 16;
        const float* src = W + ((size_t)hc * DD + d0 + i) * SS + sq;
        #pragma unroll
        for (int u = 0; u < 4; u++) {
            float4 v = *(const float4*)(src + 4 * u);
            tile[i][sq + 4 * u + 0] = v.x; tile[i][sq + 4 * u + 1] = v.y;
            tile[i][sq + 4 * u + 2] = v.z; tile[i][sq + 4 * u + 3] = v.w;
        }
    }
    __syncthreads();
    {
        int s = t >> 2, jq = (t & 3) * 16;
        _Float16 hbuf[16], lbuf[16];
        #pragma unroll
        for (int u = 0; u < 16; u++) {
            float x = tile[jq + u][s];
            _Float16 hi = (_Float16)x;
            hbuf[u] = hi;
            lbuf[u] = (_Float16)(x - (float)hi);
        }
        size_t off = (size_t)hc * SS * DD + (size_t)s * DD + d0 + jq;
        *(half8*)(Wth + off)     = *(half8*)(hbuf);
        *(half8*)(Wth + off + 8) = *(half8*)(hbuf + 8);
        *(half8*)(Wtl + off)     = *(half8*)(lbuf);
        *(half8*)(Wtl + off + 8) = *(half8*)(lbuf + 8);
    }
}

// ---------------- Kernel 1: QKV projection (exact R5 best-known) -----------
// grid (32 token-tiles, 24 hc-pairs). A-frags feed both hc's 96 MFMA.
__global__ __launch_bounds__(256, 2) void qkv_mfma(
    const _Float16* __restrict__ Xh, const _Float16* __restrict__ Xl,
    const _Float16* __restrict__ Wth, const _Float16* __restrict__ Wtl,
    _Float16* __restrict__ Qh, _Float16* __restrict__ Ql,
    _Float16* __restrict__ Kh, _Float16* __restrict__ Kl,
    _Float16* __restrict__ Vt)
{
    const int hc0 = blockIdx.y * 2;
    const int lane = threadIdx.x & 63, wave = threadIdx.x >> 6;
    const int l16 = lane & 15, quad = lane >> 4;
    const int r0 = blockIdx.x * 256 + wave * 64;

    floatx4 acc[2][4][4];
    #pragma unroll
    for (int p = 0; p < 2; p++)
        #pragma unroll
        for (int i = 0; i < 4; i++)
            #pragma unroll
            for (int j = 0; j < 4; j++) acc[p][i][j] = (floatx4){0.f, 0.f, 0.f, 0.f};

    for (int k0 = 0; k0 < DD; k0 += 32) {
        const int ka = k0 + 8 * quad;
        half8 Ah[4], Al[4];
        #pragma unroll
        for (int t = 0; t < 4; t++) {
            size_t arow = (size_t)(r0 + 16 * t + l16) * DD + ka;
            Ah[t] = *(const half8*)(Xh + arow);
            Al[t] = *(const half8*)(Xl + arow);
        }
        #pragma unroll
        for (int p = 0; p < 2; p++) {
            const _Float16* wb_h = Wth + (size_t)(hc0 + p) * SS * DD;
            const _Float16* wb_l = Wtl + (size_t)(hc0 + p) * SS * DD;
            half8 Bh[4], Bl[4];
            #pragma unroll
            for (int t = 0; t < 4; t++) {
                size_t brow = (size_t)(16 * t + l16) * DD + ka;
                Bh[t] = *(const half8*)(wb_h + brow);
                Bl[t] = *(const half8*)(wb_l + brow);
            }
            #pragma unroll
            for (int i = 0; i < 4; i++)
                #pragma unroll
                for (int j = 0; j < 4; j++)
                    acc[p][i][j] = MFMA16(Ah[i], Bh[j], acc[p][i][j]);
            #pragma unroll
            for (int i = 0; i < 4; i++)
                #pragma unroll
                for (int j = 0; j < 4; j++)
                    acc[p][i][j] = MFMA16(Ah[i], Bl[j], acc[p][i][j]);
            #pragma unroll
            for (int i = 0; i < 4; i++)
                #pragma unroll
                for (int j = 0; j < 4; j++)
                    acc[p][i][j] = MFMA16(Al[i], Bh[j], acc[p][i][j]);
        }
    }

    #pragma unroll
    for (int p = 0; p < 2; p++) {
        const int hc = hc0 + p;
        const int h = hc / 3, c = hc % 3;
        if (c == 2) {
            #pragma unroll
            for (int i = 0; i < 4; i++)
                #pragma unroll
                for (int j = 0; j < 4; j++) {
                    int tok0 = r0 + 16 * i + 4 * quad;
                    int b = tok0 >> 10, n0 = tok0 & 1023;
                    half4v pk;
                    #pragma unroll
                    for (int r = 0; r < 4; r++) pk[r] = (_Float16)acc[p][i][j][r];
                    *(half4v*)(Vt + ((size_t)(b * HH + h) * SS + 16 * j + l16) * NN + n0) = pk;
                }
        } else {
            _Float16* Ph = (c == 0) ? Qh : Kh;
            _Float16* Pl = (c == 0) ? Ql : Kl;
            #pragma unroll
            for (int i = 0; i < 4; i++)
                #pragma unroll
                for (int j = 0; j < 4; j++)
                    #pragma unroll
                    for (int r = 0; r < 4; r++) {
                        int tok = r0 + 16 * i + 4 * quad + r;
                        int b = tok >> 10, n = tok & 1023;
                        float v = acc[p][i][j][r];
                        _Float16 vh = (_Float16)v;
                        _Float16 vl = (_Float16)(v - (float)vh);
                        size_t off = ((size_t)(b * HH + h) * NN + n) * SS + 16 * j + l16;
                        Ph[off] = vh; Pl[off] = vl;
                    }
        }
    }
}

// ---------------- Kernel 2: MFMA flash attention, LDS-staged K/V -----------
// grid (128 bh, 8 qt): same-bh blocks ≡ bh (mod 8) -> same XCD, K/V L2-hot.
// 4 waves x 32 q-rows (R5's proven g=2 density, bit-identical arithmetic).
// K/V tiles staged in LDS (shared by all 4 waves), double-buffered: global
// loads for kt+1 issue BEFORE compute(kt), stores+barrier after -> a full
// body (~1000 cyc) of latency cover that the compiler cannot delete.
// 16B-granule XOR swizzle (col ^= row&7): conflict-free stores, ~8-cyc b128.
__global__ __launch_bounds__(256) void attn_mfma(
    const _Float16* __restrict__ Qh, const _Float16* __restrict__ Ql,
    const _Float16* __restrict__ Kh, const _Float16* __restrict__ Kl,
    const _Float16* __restrict__ Vt,
    const float* __restrict__ mask,
    float* __restrict__ out)
{
    const int bh = blockIdx.x, qt = blockIdx.y;
    const int b = bh >> 4, h = bh & 15;
    const int tid = threadIdx.x;
    const int wave = tid >> 6, lane = tid & 63;
    const int l16 = lane & 15, quad = lane >> 4;

    __shared__ float Ms[NN];                 //  4 KB
    __shared__ _Float16 KhS[2][64 * 64];     // 16 KB
    __shared__ _Float16 KlS[2][64 * 64];     // 16 KB
    __shared__ _Float16 VS [2][64 * 64];     // 16 KB
    __shared__ _Float16 Plds[4][32][72];     // 18 KB   total ~70 KB -> 2 blk/CU

    *(float4*)&Ms[tid * 4] = *(const float4*)(mask + b * NN + tid * 4);

    // ---- staging helpers: granule g in [0,512): row=g>>3, slot col=g&7,
    // source col c=(g&7)^(row&7)  (XOR swizzle realized by permuting source)
    half8 G[6];
    auto stage_load = [&](int kt_) {
        #pragma unroll
        for (int i = 0; i < 2; i++) {
            int g = tid + 256 * i;
            int row = g >> 3;
            int c = (g & 7) ^ (row & 7);
            size_t ko = ((size_t)bh * NN + kt_ * 64 + row) * SS + c * 8;
            G[i]     = *(const half8*)(Kh + ko);
            G[2 + i] = *(const half8*)(Kl + ko);
            G[4 + i] = *(const half8*)(Vt + ((size_t)bh * SS + row) * NN
                                       + (size_t)kt_ * 64 + c * 8);
        }
    };
    auto stage_store = [&](int buf) {
        #pragma unroll
        for (int i = 0; i < 2; i++) {
            int g = tid + 256 * i;
            *(half8*)&KhS[buf][g * 8] = G[i];
            *(half8*)&KlS[buf][g * 8] = G[2 + i];
            *(half8*)&VS [buf][g * 8] = G[4 + i];
        }
    };

    stage_load(0);
    stage_store(0);
    __syncthreads();     // Ms + buf0 ready

    const int qrow0 = qt * 128 + wave * 32;
    half8 Aqh[2][2], Aql[2][2];
    #pragma unroll
    for (int g = 0; g < 2; g++) {
        const size_t qbase = ((size_t)bh * NN + qrow0 + 16 * g + l16) * SS + quad * 8;
        Aqh[g][0] = *(const half8*)(Qh + qbase);
        Aqh[g][1] = *(const half8*)(Qh + qbase + 32);
        Aql[g][0] = *(const half8*)(Ql + qbase);
        Aql[g][1] = *(const half8*)(Ql + qbase + 32);
    }

    float qm[2][4], m_old[2][4], l_sum[2][4];
    floatx4 accO[2][4];
    #pragma unroll
    for (int g = 0; g < 2; g++) {
        #pragma unroll
        for (int r = 0; r < 4; r++) {
            qm[g][r] = Ms[qrow0 + 16 * g + quad * 4 + r];
            m_old[g][r] = -3.0e38f;
            l_sum[g][r] = 0.f;
        }
        #pragma unroll
        for (int j = 0; j < 4; j++) accO[g][j] = (floatx4){0.f, 0.f, 0.f, 0.f};
    }

    const int sw = l16 & 7;

    for (int kt = 0; kt < 16; kt++) {
        const int cur = kt & 1;
        if (kt < 15) stage_load(kt + 1);   // in flight during compute below

        // ---- S = Q K^T (fp16x3), K frags from LDS ----
        floatx4 accS[2][4];
        #pragma unroll
        for (int g = 0; g < 2; g++)
            #pragma unroll
            for (int jt = 0; jt < 4; jt++) accS[g][jt] = (floatx4){0.f, 0.f, 0.f, 0.f};
        #pragma unroll
        for (int jt = 0; jt < 4; jt++) {
            const int rowK = jt * 16 + l16;
            const _Float16* krh = &KhS[cur][rowK * 64];
            const _Float16* krl = &KlS[cur][rowK * 64];
            half8 Bh0 = *(const half8*)&krh[((quad    ) ^ sw) * 8];
            half8 Bh1 = *(const half8*)&krh[((quad + 4) ^ sw) * 8];
            half8 Bl0 = *(const half8*)&krl[((quad    ) ^ sw) * 8];
            half8 Bl1 = *(const half8*)&krl[((quad + 4) ^ sw) * 8];
            #pragma unroll
            for (int g = 0; g < 2; g++) {
                accS[g][jt] = MFMA16(Aqh[g][0], Bh0, accS[g][jt]);
                accS[g][jt] = MFMA16(Aqh[g][1], Bh1, accS[g][jt]);
                accS[g][jt] = MFMA16(Aqh[g][0], Bl0, accS[g][jt]);
                accS[g][jt] = MFMA16(Aqh[g][1], Bl1, accS[g][jt]);
                accS[g][jt] = MFMA16(Aql[g][0], Bh0, accS[g][jt]);
                accS[g][jt] = MFMA16(Aql[g][1], Bh1, accS[g][jt]);
            }
        }
        // ---- literal fp32 mask penalty (preserves ref's ulp(1e8)=8 bins) ----
        float km[4];
        #pragma unroll
        for (int jt = 0; jt < 4; jt++) km[jt] = Ms[kt * 64 + jt * 16 + l16];
        #pragma unroll
        for (int g = 0; g < 2; g++)
            #pragma unroll
            for (int jt = 0; jt < 4; jt++)
                #pragma unroll
                for (int r = 0; r < 4; r++)
                    accS[g][jt][r] -= 1.0e8f * (1.0f - qm[g][r] * km[jt]);

        // ---- online softmax (identical to R5) ----
        #pragma unroll
        for (int g = 0; g < 2; g++) {
            float alpha[4];
            #pragma unroll
            for (int r = 0; r < 4; r++) {
                float mt = fmaxf(fmaxf(accS[g][0][r], accS[g][1][r]),
                                 fmaxf(accS[g][2][r], accS[g][3][r]));
                #pragma unroll
                for (int off = 1; off < 16; off <<= 1)
                    mt = fmaxf(mt, __shfl_xor(mt, off, 64));
                float mn = fmaxf(m_old[g][r], mt);
                alpha[r] = __expf(m_old[g][r] - mn);
                m_old[g][r] = mn;
                float ls = 0.f;
                #pragma unroll
                for (int jt = 0; jt < 4; jt++) {
                    float pj = __expf(accS[g][jt][r] - mn);
                    accS[g][jt][r] = pj;
                    ls += pj;
                }
                #pragma unroll
                for (int off = 1; off < 16; off <<= 1)
                    ls += __shfl_xor(ls, off, 64);
                l_sum[g][r] = l_sum[g][r] * alpha[r] + ls;
            }
            #pragma unroll
            for (int j = 0; j < 4; j++)
                #pragma unroll
                for (int r = 0; r < 4; r++)
                    accO[g][j][r] *= alpha[r];

            // P -> LDS (C/D -> A layout), XOR col-swizzle by row-quad
            #pragma unroll
            for (int jt = 0; jt < 4; jt++)
                #pragma unroll
                for (int r = 0; r < 4; r++)
                    Plds[wave][16 * g + quad * 4 + r][((jt ^ quad) << 4) + l16] =
                        (_Float16)accS[g][jt][r];
        }

        // ---- O += P V, V frags from LDS ----
        #pragma unroll
        for (int ks = 0; ks < 2; ks++) {
            int cbase = (((2 * ks + (quad >> 1)) ^ (l16 >> 2)) << 4) + (quad & 1) * 8;
            half8 Ap[2];
            #pragma unroll
            for (int g = 0; g < 2; g++)
                Ap[g] = *(const half8*)&Plds[wave][16 * g + l16][cbase];
            #pragma unroll
            for (int j = 0; j < 4; j++) {
                half8 Bv = *(const half8*)&VS[cur][(j * 16 + l16) * 64
                                                   + (((ks * 4 + quad) ^ sw) * 8)];
                #pragma unroll
                for (int g = 0; g < 2; g++)
                    accO[g][j] = MFMA16(Ap[g], Bv, accO[g][j]);
            }
        }

        if (kt < 15) {
            stage_store(1 - cur);   // waits the in-flight loads, fills next buf
            __syncthreads();
        }
    }

    // ---- epilogue: out[b, n, s*16 + h] ----
    #pragma unroll
    for (int g = 0; g < 2; g++)
        #pragma unroll
        for (int r = 0; r < 4; r++) {
            float inv = 1.f / l_sum[g][r];
            int qrow = qrow0 + 16 * g + quad * 4 + r;
            #pragma unroll
            for (int j = 0; j < 4; j++)
                out[((size_t)(b * NN + qrow)) * (SS * HH) + (j * 16 + l16) * HH + h] =
                    accO[g][j][r] * inv;
        }
}

// ================= fp32 fallback path (R2, known-good) =================
__global__ __launch_bounds__(256) void qkv_kernel(
    const float* __restrict__ X, const float* __restrict__ W, float* __restrict__ qkv)
{
    const int ttile = blockIdx.x;
    const int hc    = blockIdx.y;
    const int h     = hc / 3, c = hc % 3;
    const int tid = threadIdx.x;
    const int tx = tid & 15, ty = tid >> 4;
    __shared__ float As[32][68];
    __shared__ float Bs[32][68];
    const float* Wb = W + (size_t)hc * DD * SS;
    const int row0 = ttile * 64;
    float acc[4][4];
    #pragma unroll
    for (int i = 0; i < 4; i++)
        #pragma unroll
        for (int j = 0; j < 4; j++) acc[i][j] = 0.f;
    for (int k0 = 0; k0 < DD; k0 += 32) {
        #pragma unroll
        for (int l = 0; l < 2; l++) {
            int i = tid + l * 256;
            int r = i >> 3;
            int kq = (i & 7) * 4;
            float4 x4 = *(const float4*)(X + (size_t)(row0 + r) * DD + k0 + kq);
            As[kq + 0][r] = x4.x; As[kq + 1][r] = x4.y;
            As[kq + 2][r] = x4.z; As[kq + 3][r] = x4.w;
        }
        #pragma unroll
        for (int l = 0; l < 2; l++) {
            int i = tid + l * 256;
            int kr = i >> 4;
            int sq = (i & 15) * 4;
            *(float4*)&Bs[kr][sq] = *(const float4*)(Wb + (size_t)(k0 + kr) * SS + sq);
        }
        __syncthreads();
        #pragma unroll
        for (int kk = 0; kk < 32; kk++) {
            float4 a4 = *(const float4*)&As[kk][ty * 4];
            float4 b4 = *(const float4*)&Bs[kk][tx * 4];
            float a[4] = {a4.x, a4.y, a4.z, a4.w};
            float bb[4] = {b4.x, b4.y, b4.z, b4.w};
            #pragma unroll
            for (int i = 0; i < 4; i++)
                #pragma unroll
                for (int j = 0; j < 4; j++)
                    acc[i][j] = fmaf(a[i], bb[j], acc[i][j]);
        }
        __syncthreads();
    }
    float* outp = qkv + (size_t)c * BH * NN * SS;
    #pragma unroll
    for (int i = 0; i < 4; i++) {
        int tg = row0 + ty * 4 + i;
        int b = tg >> 10, n = tg & 1023;
        float4 v4 = make_float4(acc[i][0], acc[i][1], acc[i][2], acc[i][3]);
        *(float4*)(outp + ((size_t)(b * HH + h) * NN + n) * SS + tx * 4) = v4;
    }
}

__global__ __launch_bounds__(256) void attn_kernel(
    const float* __restrict__ qkv,
    const float* __restrict__ mask,
    float* __restrict__ out)
{
    const int qt = blockIdx.x, h = blockIdx.y, b = blockIdx.z;
    const int tid = threadIdx.x;
    const int tx = tid & 15, ty = tid >> 4;
    const int bh = b * HH + h;
    const float* Q = qkv + (size_t)bh * NN * SS;
    const float* K = qkv + (size_t)BH * NN * SS + (size_t)bh * NN * SS;
    const float* V = qkv + 2 * (size_t)BH * NN * SS + (size_t)bh * NN * SS;

    __shared__ float QsT[64][68];
    __shared__ float KsT[64][68];
    __shared__ float Vs [64][68];
    __shared__ float PsT[64][68];
    __shared__ float Ms[NN];

    {
        float4 mm = *(const float4*)(mask + b * NN + tid * 4);
        *(float4*)&Ms[tid * 4] = mm;
    }
    #pragma unroll
    for (int l = 0; l < 4; l++) {
        int i = tid + l * 256;
        int r = i >> 4, sq = (i & 15) * 4;
        float4 x4 = *(const float4*)(Q + (size_t)(qt * 64 + r) * SS + sq);
        QsT[sq + 0][r] = x4.x; QsT[sq + 1][r] = x4.y;
        QsT[sq + 2][r] = x4.z; QsT[sq + 3][r] = x4.w;
    }
    __syncthreads();

    float m_old[4], l_sum[4], O[4][4], qm[4];
    #pragma unroll
    for (int i = 0; i < 4; i++) {
        qm[i] = Ms[qt * 64 + ty * 4 + i];
        m_old[i] = -3.0e38f; l_sum[i] = 0.f;
        #pragma unroll
        for (int j = 0; j < 4; j++) O[i][j] = 0.f;
    }

    for (int kt = 0; kt < 16; kt++) {
        #pragma unroll
        for (int l = 0; l < 4; l++) {
            int i = tid + l * 256;
            int r = i >> 4, sq = (i & 15) * 4;
            float4 k4 = *(const float4*)(K + (size_t)(kt * 64 + r) * SS + sq);
            KsT[sq + 0][r] = k4.x; KsT[sq + 1][r] = k4.y;
            KsT[sq + 2][r] = k4.z; KsT[sq + 3][r] = k4.w;
            float4 v4 = *(const float4*)(V + (size_t)(kt * 64 + r) * SS + sq);
            *(float4*)&Vs[r][sq] = v4;
        }
        __syncthreads();

        float sc[4][4];
        #pragma unroll
        for (int i = 0; i < 4; i++)
            #pragma unroll
            for (int j = 0; j < 4; j++) sc[i][j] = 0.f;
        #pragma unroll 8
        for (int s = 0; s < 64; s++) {
            float4 a4 = *(const float4*)&QsT[s][ty * 4];
            float4 b4 = *(const float4*)&KsT[s][tx * 4];
            float a[4] = {a4.x, a4.y, a4.z, a4.w};
            float bb[4] = {b4.x, b4.y, b4.z, b4.w};
            #pragma unroll
            for (int i = 0; i < 4; i++)
                #pragma unroll
                for (int j = 0; j < 4; j++)
                    sc[i][j] = fmaf(a[i], bb[j], sc[i][j]);
        }
        float km[4];
        #pragma unroll
        for (int j = 0; j < 4; j++) km[j] = Ms[kt * 64 + tx * 4 + j];
        #pragma unroll
        for (int i = 0; i < 4; i++)
            #pragma unroll
            for (int j = 0; j < 4; j++) {
                float pen = 1.0e8f * (1.0f - qm[i] * km[j]);
                sc[i][j] = sc[i][j] - pen;
            }

        #pragma unroll
        for (int i = 0; i < 4; i++) {
            float mt = fmaxf(fmaxf(sc[i][0], sc[i][1]), fmaxf(sc[i][2], sc[i][3]));
            #pragma unroll
            for (int off = 1; off < 16; off <<= 1)
                mt = fmaxf(mt, __shfl_xor(mt, off, 64));
            float mn = fmaxf(m_old[i], mt);
            float alpha = __expf(m_old[i] - mn);
            float p[4];
            #pragma unroll
            for (int j = 0; j < 4; j++) p[j] = __expf(sc[i][j] - mn);
            float ls = (p[0] + p[1]) + (p[2] + p[3]);
            #pragma unroll
            for (int off = 1; off < 16; off <<= 1)
                ls += __shfl_xor(ls, off, 64);
            l_sum[i] = l_sum[i] * alpha + ls;
            m_old[i] = mn;
            #pragma unroll
            for (int j = 0; j < 4; j++) {
                O[i][j] *= alpha;
                PsT[tx * 4 + j][ty * 4 + i] = p[j];
            }
        }
        __syncthreads();

        #pragma unroll 8
        for (int kj = 0; kj < 64; kj++) {
            float4 p4 = *(const float4*)&PsT[kj][ty * 4];
            float4 v4 = *(const float4*)&Vs[kj][tx * 4];
            float p[4] = {p4.x, p4.y, p4.z, p4.w};
            float vv[4] = {v4.x, v4.y, v4.z, v4.w};
            #pragma unroll
            for (int i = 0; i < 4; i++)
                #pragma unroll
                for (int j = 0; j < 4; j++)
                    O[i][j] = fmaf(p[i], vv[j], O[i][j]);
        }
        __syncthreads();
    }

    #pragma unroll
    for (int i = 0; i < 4; i++) {
        int qrow = qt * 64 + ty * 4 + i;
        float inv = 1.f / l_sum[i];
        #pragma unroll
        for (int j = 0; j < 4; j++) {
            int s = tx * 4 + j;
            out[((size_t)(b * NN + qrow)) * (SS * HH) + s * HH + h] = O[i][j] * inv;
        }
    }
}

extern "C" void kernel_launch(void* const* d_in, const int* in_sizes, int n_in,
                              void* d_out, int out_size, void* d_ws, size_t ws_size,
                              hipStream_t stream) {
    const float* X    = (const float*)d_in[0];   // [8,1024,1024]
    const float* mask = (const float*)d_in[1];   // [8,1024]
    const float* W    = (const float*)d_in[2];   // [16,3,1024,64]
    float* out = (float*)d_out;

    const size_t x_elems  = (size_t)BB * NN * DD;       // 8,388,608
    const size_t w_elems  = (size_t)HH * 3 * SS * DD;   // 3,145,728
    const size_t qk_elems = (size_t)BH * NN * SS;       // 8,388,608
    const size_t need_fast = (2 * x_elems + 2 * w_elems + 5 * qk_elems) * sizeof(_Float16); // ~130 MB

    if (ws_size >= need_fast) {
        _Float16* Xh  = (_Float16*)d_ws;
        _Float16* Xl  = Xh  + x_elems;
        _Float16* Wth = Xl  + x_elems;
        _Float16* Wtl = Wth + w_elems;
        _Float16* Qh  = Wtl + w_elems;
        _Float16* Ql  = Qh  + qk_elems;
        _Float16* Kh  = Ql  + qk_elems;
        _Float16* Kl  = Kh  + qk_elems;
        _Float16* Vt  = Kl  + qk_elems;

        split_x<<<dim3((unsigned)(x_elems / 1024)), dim3(256), 0, stream>>>(X, Xh, Xl);
        split_wt<<<dim3(48, 16), dim3(256), 0, stream>>>(W, Wth, Wtl);
        qkv_mfma<<<dim3(32, 24), dim3(256), 0, stream>>>(Xh, Xl, Wth, Wtl, Qh, Ql, Kh, Kl, Vt);
        attn_mfma<<<dim3(128, 8), dim3(256), 0, stream>>>(Qh, Ql, Kh, Kl, Vt, mask, out);
    } else if (ws_size >= 3ull * BH * NN * SS * sizeof(float)) {
        float* qkv = (float*)d_ws;
        qkv_kernel<<<dim3(128, 48), dim3(256), 0, stream>>>(X, W, qkv);
        attn_kernel<<<dim3(16, 16, 8), dim3(256), 0, stream>>>(qkv, mask, out);
    }
}